// Round 1
// baseline (196.662 us; speedup 1.0000x reference)
//
#include <hip/hip_runtime.h>

#define N_PTS 8192
#define DX 128
#define DY 64
#define PITCH 72   // 64 + 8 bf16 pad: row stride 144B -> 2-way bank aliasing (free)

typedef __bf16 bf16x8 __attribute__((ext_vector_type(8)));
typedef float f32x4 __attribute__((ext_vector_type(4)));
typedef unsigned short u16x8 __attribute__((ext_vector_type(8)));

__device__ inline unsigned short f32_to_bf16_rne(float f) {
  unsigned int u = __float_as_uint(f);
  u += 0x7fff + ((u >> 16) & 1);
  return (unsigned short)(u >> 16);
}

// Convert fp32 -> bf16 (RNE) and compute per-row squared norm of the ROUNDED
// values (so MFMA diagonal dist^2 == 0 to fp32 rounding).
__global__ void prep_kernel(const float* __restrict__ src,
                            unsigned short* __restrict__ dst,
                            float* __restrict__ sq, int D) {
  int row = blockIdx.x * 4 + (threadIdx.x >> 6);
  int lane = threadIdx.x & 63;
  const float* s = src + (long)row * D;
  unsigned short* d = dst + (long)row * D;
  float acc = 0.f;
  for (int c = lane; c < D; c += 64) {
    unsigned short b = f32_to_bf16_rne(s[c]);
    d[c] = b;
    float bv = __uint_as_float(((unsigned int)b) << 16);
    acc += bv * bv;
  }
  #pragma unroll
  for (int m = 32; m >= 1; m >>= 1) acc += __shfl_xor(acc, m);
  if (lane == 0) sq[row] = acc;
}

// One block per 128x128 tile of the (i,j) pair space.
// Computes inner_x and inner_y tiles via MFMA, then K = exp(-d^2/2) epilogue,
// accumulating S1 partial (per block), row sums rX, rY (atomics).
__global__ __launch_bounds__(256, 2)
void tiles_kernel(const unsigned short* __restrict__ xb,
                  const unsigned short* __restrict__ yb,
                  const float* __restrict__ sqx,
                  const float* __restrict__ sqy,
                  float* __restrict__ rX, float* __restrict__ rY,
                  float* __restrict__ S1arr) {
  __shared__ unsigned short Abuf[128 * PITCH];
  __shared__ unsigned short Bbuf[128 * PITCH];
  __shared__ float sq_is[2][128];  // [0]=x, [1]=y, rows I
  __shared__ float sq_js[2][128];  // cols J
  __shared__ float red[4];

  const int bj = blockIdx.x, bi = blockIdx.y;
  const int t = threadIdx.x;
  const int lane = t & 63, w = t >> 6;
  const int quad = lane >> 4, c0 = lane & 15;
  const int I = bi * 128, J = bj * 128;
  const int cc = t & 7, r0 = t >> 3;  // staging: 8 x 16B chunks per 64-col row

  f32x4 accx[2][8], accy[2][8];
  const f32x4 zero = {0.f, 0.f, 0.f, 0.f};
  #pragma unroll
  for (int a = 0; a < 2; ++a)
    #pragma unroll
    for (int b = 0; b < 8; ++b) { accx[a][b] = zero; accy[a][b] = zero; }

  // ---- phase 1: stage Y tiles (K=64 entire) + sq ----
  #pragma unroll
  for (int p = 0; p < 4; ++p) {
    int r = r0 + p * 32;
    *(u16x8*)&Abuf[r * PITCH + cc * 8] = *(const u16x8*)&yb[(long)(I + r) * DY + cc * 8];
    *(u16x8*)&Bbuf[r * PITCH + cc * 8] = *(const u16x8*)&yb[(long)(J + r) * DY + cc * 8];
  }
  if (t < 128) { sq_is[0][t] = sqx[I + t]; sq_is[1][t] = sqy[I + t]; }
  else { int u = t - 128; sq_js[0][u] = sqx[J + u]; sq_js[1][u] = sqy[J + u]; }
  __syncthreads();

  // ---- Y MFMA ----
  #pragma unroll
  for (int ks = 0; ks < 2; ++ks) {
    int koff = ks * 32 + quad * 8;
    bf16x8 a0 = *(const bf16x8*)&Abuf[(w * 32 + 0  + c0) * PITCH + koff];
    bf16x8 a1 = *(const bf16x8*)&Abuf[(w * 32 + 16 + c0) * PITCH + koff];
    #pragma unroll
    for (int tn = 0; tn < 8; ++tn) {
      bf16x8 b = *(const bf16x8*)&Bbuf[(tn * 16 + c0) * PITCH + koff];
      accy[0][tn] = __builtin_amdgcn_mfma_f32_16x16x32_bf16(a0, b, accy[0][tn], 0, 0, 0);
      accy[1][tn] = __builtin_amdgcn_mfma_f32_16x16x32_bf16(a1, b, accy[1][tn], 0, 0, 0);
    }
  }

  // ---- X in two K-chunks of 64, reusing the same LDS buffers ----
  #pragma unroll
  for (int h = 0; h < 2; ++h) {
    __syncthreads();
    #pragma unroll
    for (int p = 0; p < 4; ++p) {
      int r = r0 + p * 32;
      *(u16x8*)&Abuf[r * PITCH + cc * 8] = *(const u16x8*)&xb[(long)(I + r) * DX + h * 64 + cc * 8];
      *(u16x8*)&Bbuf[r * PITCH + cc * 8] = *(const u16x8*)&xb[(long)(J + r) * DX + h * 64 + cc * 8];
    }
    __syncthreads();
    #pragma unroll
    for (int ks = 0; ks < 2; ++ks) {
      int koff = ks * 32 + quad * 8;
      bf16x8 a0 = *(const bf16x8*)&Abuf[(w * 32 + 0  + c0) * PITCH + koff];
      bf16x8 a1 = *(const bf16x8*)&Abuf[(w * 32 + 16 + c0) * PITCH + koff];
      #pragma unroll
      for (int tn = 0; tn < 8; ++tn) {
        bf16x8 b = *(const bf16x8*)&Bbuf[(tn * 16 + c0) * PITCH + koff];
        accx[0][tn] = __builtin_amdgcn_mfma_f32_16x16x32_bf16(a0, b, accx[0][tn], 0, 0, 0);
        accx[1][tn] = __builtin_amdgcn_mfma_f32_16x16x32_bf16(a1, b, accx[1][tn], 0, 0, 0);
      }
    }
  }

  // ---- epilogue: K = exp(-d^2/2); accumulate S1, rX, rY ----
  // C/D layout (16x16x32): col = lane&15, row = quad*4 + reg  [m89/m91]
  float s1 = 0.f;
  #pragma unroll
  for (int tm = 0; tm < 2; ++tm) {
    #pragma unroll
    for (int r = 0; r < 4; ++r) {
      int il = w * 32 + tm * 16 + quad * 4 + r;
      float sxi = sq_is[0][il], syi = sq_is[1][il];
      float rxp = 0.f, ryp = 0.f;
      #pragma unroll
      for (int tn = 0; tn < 8; ++tn) {
        int jl = tn * 16 + c0;
        float dx = sxi + sq_js[0][jl] - 2.f * accx[tm][tn][r];
        float dy = syi + sq_js[1][jl] - 2.f * accy[tm][tn][r];
        float kx = __expf(-0.5f * dx);
        float ky = __expf(-0.5f * dy);
        rxp += kx; ryp += ky; s1 += kx * ky;
      }
      // reduce across the 16 lanes of this quad (c0 dimension)
      rxp += __shfl_xor(rxp, 1); rxp += __shfl_xor(rxp, 2);
      rxp += __shfl_xor(rxp, 4); rxp += __shfl_xor(rxp, 8);
      ryp += __shfl_xor(ryp, 1); ryp += __shfl_xor(ryp, 2);
      ryp += __shfl_xor(ryp, 4); ryp += __shfl_xor(ryp, 8);
      if (c0 == 0) {
        atomicAdd(&rX[I + il], rxp);
        atomicAdd(&rY[I + il], ryp);
      }
    }
  }
  #pragma unroll
  for (int m = 32; m >= 1; m >>= 1) s1 += __shfl_xor(s1, m);
  if (lane == 0) red[w] = s1;
  __syncthreads();
  if (t == 0) S1arr[bi * 64 + bj] = red[0] + red[1] + red[2] + red[3];
}

__global__ void finalize_kernel(const float* __restrict__ rX, const float* __restrict__ rY,
                                const float* __restrict__ S1arr, float* __restrict__ out) {
  int t = threadIdx.x;
  float dot = 0.f, tx = 0.f, ty = 0.f, s1 = 0.f;
  for (int i = t; i < N_PTS; i += 512) {
    float a = rX[i], b = rY[i];
    dot += a * b; tx += a; ty += b;
  }
  for (int i = t; i < 4096; i += 512) s1 += S1arr[i];
  #pragma unroll
  for (int m = 32; m >= 1; m >>= 1) {
    dot += __shfl_xor(dot, m); tx += __shfl_xor(tx, m);
    ty  += __shfl_xor(ty, m);  s1 += __shfl_xor(s1, m);
  }
  __shared__ float sd[8], sx[8], sy[8], ss[8];
  int w = t >> 6, lane = t & 63;
  if (lane == 0) { sd[w] = dot; sx[w] = tx; sy[w] = ty; ss[w] = s1; }
  __syncthreads();
  if (t == 0) {
    double D = 0, X = 0, Y = 0, S = 0;
    for (int i = 0; i < 8; ++i) { D += sd[i]; X += sx[i]; Y += sy[i]; S += ss[i]; }
    double n = (double)N_PTS;
    out[0] = (float)(S - (2.0 / n) * D + (X * Y) / (n * n));
  }
}

extern "C" void kernel_launch(void* const* d_in, const int* in_sizes, int n_in,
                              void* d_out, int out_size, void* d_ws, size_t ws_size,
                              hipStream_t stream) {
  const float* x = (const float*)d_in[0];
  const float* y = (const float*)d_in[1];
  char* ws = (char*)d_ws;
  unsigned short* xb = (unsigned short*)(ws);                 // 8192*128*2 = 2 MB
  unsigned short* yb = (unsigned short*)(ws + 2097152);       // 8192*64*2  = 1 MB
  float* sqx = (float*)(ws + 3145728);                        // 32 KB
  float* sqy = (float*)(ws + 3178496);                        // 32 KB
  float* rX  = (float*)(ws + 3211264);                        // 32 KB (zeroed)
  float* rY  = (float*)(ws + 3244032);                        // 32 KB (zeroed)
  float* S1arr = (float*)(ws + 3276800);                      // 4096 floats (fully overwritten)

  hipMemsetAsync(rX, 0, 65536, stream);  // rX + rY contiguous
  prep_kernel<<<2048, 256, 0, stream>>>(x, xb, sqx, DX);
  prep_kernel<<<2048, 256, 0, stream>>>(y, yb, sqy, DY);
  tiles_kernel<<<dim3(64, 64), 256, 0, stream>>>(xb, yb, sqx, sqy, rX, rY, S1arr);
  finalize_kernel<<<1, 512, 0, stream>>>(rX, rY, S1arr, (float*)d_out);
}

// Round 2
// 126.580 us; speedup vs baseline: 1.5537x; 1.5537x over previous
//
#include <hip/hip_runtime.h>

#define N_PTS 8192
#define DX 128
#define DY 64
#define NB 64          // 128-row blocks
#define NTILES 2080    // NB*(NB+1)/2 upper-triangle tiles
#define PITCH 72       // 64 + 8 bf16 pad

typedef __bf16 bf16x8 __attribute__((ext_vector_type(8)));
typedef float f32x4 __attribute__((ext_vector_type(4)));
typedef float f32x4v __attribute__((ext_vector_type(4)));
typedef unsigned short u16x8 __attribute__((ext_vector_type(8)));

__device__ inline unsigned short f32_to_bf16_rne(float f) {
  unsigned int u = __float_as_uint(f);
  u += 0x7fff + ((u >> 16) & 1);
  return (unsigned short)(u >> 16);
}

// Fused prep: bf16-convert x (blocks 0..2047) and y (blocks 2048..4095),
// computing per-row sq norms of the ROUNDED values. Blocks 0..15 also zero
// the rX/rY accumulators (16384 floats).
__global__ void prep_kernel(const float* __restrict__ xs, const float* __restrict__ ys,
                            unsigned short* __restrict__ xb, unsigned short* __restrict__ yb,
                            float* __restrict__ sqx, float* __restrict__ sqy,
                            float* __restrict__ rXY) {
  int b = blockIdx.x;
  int w = threadIdx.x >> 6, lane = threadIdx.x & 63;
  if (b < 16) {
    int idx = b * 1024 + threadIdx.x * 4;
    *(f32x4v*)&rXY[idx] = (f32x4v){0.f, 0.f, 0.f, 0.f};
  }
  const float* src; unsigned short* dst; float* sq; int D, row;
  if (b < 2048) { row = b * 4 + w; src = xs; dst = xb; sq = sqx; D = DX; }
  else          { row = (b - 2048) * 4 + w; src = ys; dst = yb; sq = sqy; D = DY; }
  const float* s = src + (long)row * D;
  unsigned short* d = dst + (long)row * D;
  float acc = 0.f;
  for (int c = lane; c < D; c += 64) {
    unsigned short v = f32_to_bf16_rne(s[c]);
    d[c] = v;
    float bv = __uint_as_float(((unsigned int)v) << 16);
    acc += bv * bv;
  }
  #pragma unroll
  for (int m = 32; m >= 1; m >>= 1) acc += __shfl_xor(acc, m);
  if (lane == 0) sq[row] = acc;
}

// MFMA sweep over one K=64 chunk held in (A,B) LDS buffers.
// acc layout: acc[tm][tn], tm in {0,1} selects row sub-tile (w*32 + tm*16).
__device__ __forceinline__ void mfma_chunk(const unsigned short* __restrict__ A,
                                           const unsigned short* __restrict__ B,
                                           f32x4 acc[2][8], int w, int quad, int c0) {
  #pragma unroll
  for (int ks = 0; ks < 2; ++ks) {
    int koff = ks * 32 + quad * 8;
    bf16x8 a0 = *(const bf16x8*)&A[(w * 32 + 0  + c0) * PITCH + koff];
    bf16x8 a1 = *(const bf16x8*)&A[(w * 32 + 16 + c0) * PITCH + koff];
    #pragma unroll
    for (int tn = 0; tn < 8; ++tn) {
      bf16x8 b = *(const bf16x8*)&B[(tn * 16 + c0) * PITCH + koff];
      acc[0][tn] = __builtin_amdgcn_mfma_f32_16x16x32_bf16(a0, b, acc[0][tn], 0, 0, 0);
      acc[1][tn] = __builtin_amdgcn_mfma_f32_16x16x32_bf16(a1, b, acc[1][tn], 0, 0, 0);
    }
  }
}

// One block per upper-triangle 128x128 tile (bi <= bj).
__global__ __launch_bounds__(256, 2)
void tiles_kernel(const unsigned short* __restrict__ xb,
                  const unsigned short* __restrict__ yb,
                  const float* __restrict__ sqx,
                  const float* __restrict__ sqy,
                  float* __restrict__ rX, float* __restrict__ rY,
                  float* __restrict__ S1arr) {
  __shared__ unsigned short YA[128 * PITCH], YB[128 * PITCH];
  __shared__ unsigned short XA[128 * PITCH], XB[128 * PITCH];
  __shared__ float sq_is[2][128], sq_js[2][128];
  __shared__ float red[4];

  // linear tile index -> (bi, bj), bi <= bj
  const int q = blockIdx.x;
  double disc = 16641.0 - 8.0 * q;           // (2*NB+1)^2 - 8q
  int bi = (int)((129.0 - __builtin_sqrt(disc)) * 0.5);
  // rowstart(i) = i*NB - i*(i-1)/2
  while ((bi + 1) * NB - ((bi + 1) * bi) / 2 <= q) ++bi;
  while (bi * NB - (bi * (bi - 1)) / 2 > q) --bi;
  const int bj = bi + (q - (bi * NB - (bi * (bi - 1)) / 2));
  const int I = bi * 128, J = bj * 128;

  const int t = threadIdx.x;
  const int lane = t & 63, w = t >> 6;
  const int quad = lane >> 4, c0 = lane & 15;
  const int cc = t & 7, r0 = t >> 3;

  f32x4 accx[2][8], accy[2][8];
  const f32x4 zero = {0.f, 0.f, 0.f, 0.f};
  #pragma unroll
  for (int a = 0; a < 2; ++a)
    #pragma unroll
    for (int b = 0; b < 8; ++b) { accx[a][b] = zero; accy[a][b] = zero; }

  // ---- phase 1: stage Y (both sides) AND X chunk h=0 ----
  #pragma unroll
  for (int p = 0; p < 4; ++p) {
    int r = r0 + p * 32;
    *(u16x8*)&YA[r * PITCH + cc * 8] = *(const u16x8*)&yb[(long)(I + r) * DY + cc * 8];
    *(u16x8*)&YB[r * PITCH + cc * 8] = *(const u16x8*)&yb[(long)(J + r) * DY + cc * 8];
    *(u16x8*)&XA[r * PITCH + cc * 8] = *(const u16x8*)&xb[(long)(I + r) * DX + cc * 8];
    *(u16x8*)&XB[r * PITCH + cc * 8] = *(const u16x8*)&xb[(long)(J + r) * DX + cc * 8];
  }
  if (t < 128) { sq_is[0][t] = sqx[I + t]; sq_is[1][t] = sqy[I + t]; }
  else { int u = t - 128; sq_js[0][u] = sqx[J + u]; sq_js[1][u] = sqy[J + u]; }
  __syncthreads();

  // ---- phase 2: MFMA Y ----
  mfma_chunk(YA, YB, accy, w, quad, c0);
  __syncthreads();   // Y buffers now free for X chunk 1

  // ---- phase 3: prefetch X h=1 to regs, MFMA X h=0 under the load latency,
  //      then spill prefetch to the (free) Y buffers ----
  u16x8 pa[4], pb[4];
  #pragma unroll
  for (int p = 0; p < 4; ++p) {
    int r = r0 + p * 32;
    pa[p] = *(const u16x8*)&xb[(long)(I + r) * DX + 64 + cc * 8];
    pb[p] = *(const u16x8*)&xb[(long)(J + r) * DX + 64 + cc * 8];
  }
  mfma_chunk(XA, XB, accx, w, quad, c0);
  #pragma unroll
  for (int p = 0; p < 4; ++p) {
    int r = r0 + p * 32;
    *(u16x8*)&YA[r * PITCH + cc * 8] = pa[p];
    *(u16x8*)&YB[r * PITCH + cc * 8] = pb[p];
  }
  __syncthreads();

  // ---- phase 4: MFMA X h=1 ----
  mfma_chunk(YA, YB, accx, w, quad, c0);

  // ---- epilogue: K = exp(-d^2/2); S1, row sums, (off-diag) col sums ----
  // C/D layout (16x16x32): col = lane&15, row = quad*4 + reg  [m89/m91]
  float s1 = 0.f;
  float colx[8], coly[8];
  #pragma unroll
  for (int tn = 0; tn < 8; ++tn) { colx[tn] = 0.f; coly[tn] = 0.f; }

  #pragma unroll
  for (int tm = 0; tm < 2; ++tm) {
    #pragma unroll
    for (int r = 0; r < 4; ++r) {
      int il = w * 32 + tm * 16 + quad * 4 + r;
      float sxi = sq_is[0][il], syi = sq_is[1][il];
      float rxp = 0.f, ryp = 0.f;
      #pragma unroll
      for (int tn = 0; tn < 8; ++tn) {
        int jl = tn * 16 + c0;
        float dx = sxi + sq_js[0][jl] - 2.f * accx[tm][tn][r];
        float dy = syi + sq_js[1][jl] - 2.f * accy[tm][tn][r];
        float kx = __expf(-0.5f * dx);
        float ky = __expf(-0.5f * dy);
        rxp += kx; ryp += ky; s1 += kx * ky;
        colx[tn] += kx; coly[tn] += ky;
      }
      rxp += __shfl_xor(rxp, 1); rxp += __shfl_xor(rxp, 2);
      rxp += __shfl_xor(rxp, 4); rxp += __shfl_xor(rxp, 8);
      ryp += __shfl_xor(ryp, 1); ryp += __shfl_xor(ryp, 2);
      ryp += __shfl_xor(ryp, 4); ryp += __shfl_xor(ryp, 8);
      if (c0 == 0) {
        atomicAdd(&rX[I + il], rxp);
        atomicAdd(&rY[I + il], ryp);
      }
    }
  }

  if (bi != bj) {
    // column sums = transposed tile's row sums -> rows J
    #pragma unroll
    for (int tn = 0; tn < 8; ++tn) {
      float cx = colx[tn], cy = coly[tn];
      cx += __shfl_xor(cx, 16); cx += __shfl_xor(cx, 32);
      cy += __shfl_xor(cy, 16); cy += __shfl_xor(cy, 32);
      if (quad == 0) {
        atomicAdd(&rX[J + tn * 16 + c0], cx);
        atomicAdd(&rY[J + tn * 16 + c0], cy);
      }
    }
    s1 *= 2.f;
  }

  #pragma unroll
  for (int m = 32; m >= 1; m >>= 1) s1 += __shfl_xor(s1, m);
  if (lane == 0) red[w] = s1;
  __syncthreads();
  if (t == 0) S1arr[q] = red[0] + red[1] + red[2] + red[3];
}

__global__ void finalize_kernel(const float* __restrict__ rX, const float* __restrict__ rY,
                                const float* __restrict__ S1arr, float* __restrict__ out) {
  int t = threadIdx.x;
  float dot = 0.f, tx = 0.f, ty = 0.f, s1 = 0.f;
  for (int i = t; i < N_PTS; i += 512) {
    float a = rX[i], b = rY[i];
    dot += a * b; tx += a; ty += b;
  }
  for (int i = t; i < NTILES; i += 512) s1 += S1arr[i];
  #pragma unroll
  for (int m = 32; m >= 1; m >>= 1) {
    dot += __shfl_xor(dot, m); tx += __shfl_xor(tx, m);
    ty  += __shfl_xor(ty, m);  s1 += __shfl_xor(s1, m);
  }
  __shared__ float sd[8], sx[8], sy[8], ss[8];
  int w = t >> 6, lane = t & 63;
  if (lane == 0) { sd[w] = dot; sx[w] = tx; sy[w] = ty; ss[w] = s1; }
  __syncthreads();
  if (t == 0) {
    double D = 0, X = 0, Y = 0, S = 0;
    for (int i = 0; i < 8; ++i) { D += sd[i]; X += sx[i]; Y += sy[i]; S += ss[i]; }
    double n = (double)N_PTS;
    out[0] = (float)(S - (2.0 / n) * D + (X * Y) / (n * n));
  }
}

extern "C" void kernel_launch(void* const* d_in, const int* in_sizes, int n_in,
                              void* d_out, int out_size, void* d_ws, size_t ws_size,
                              hipStream_t stream) {
  const float* x = (const float*)d_in[0];
  const float* y = (const float*)d_in[1];
  char* ws = (char*)d_ws;
  unsigned short* xb = (unsigned short*)(ws);                 // 2 MB
  unsigned short* yb = (unsigned short*)(ws + 2097152);       // 1 MB
  float* sqx = (float*)(ws + 3145728);                        // 32 KB
  float* sqy = (float*)(ws + 3178496);                        // 32 KB
  float* rXY = (float*)(ws + 3211264);                        // rX+rY, 64 KB (zeroed by prep)
  float* rX  = rXY;
  float* rY  = rXY + N_PTS;
  float* S1arr = (float*)(ws + 3276800);                      // 2080 floats (fully written)

  prep_kernel<<<4096, 256, 0, stream>>>(x, y, xb, yb, sqx, sqy, rXY);
  tiles_kernel<<<NTILES, 256, 0, stream>>>(xb, yb, sqx, sqy, rX, rY, S1arr);
  finalize_kernel<<<1, 512, 0, stream>>>(rX, rY, S1arr, (float*)d_out);
}

// Round 3
// 109.073 us; speedup vs baseline: 1.8030x; 1.1605x over previous
//
#include <hip/hip_runtime.h>

#define N_PTS 8192
#define DX 128
#define DY 64
#define NB 64          // 128-row blocks
#define NTILES 2080    // NB*(NB+1)/2 upper-triangle tiles
#define PITCH 72       // 64 + 8 bf16 pad: 144B row stride -> 2-way bank aliasing (free)

typedef __bf16 bf16x8 __attribute__((ext_vector_type(8)));
typedef float f32x4 __attribute__((ext_vector_type(4)));
typedef unsigned short u16x8 __attribute__((ext_vector_type(8)));
typedef unsigned short u16x4 __attribute__((ext_vector_type(4)));

__device__ inline unsigned short f32_to_bf16_rne(float f) {
  unsigned int u = __float_as_uint(f);
  u += 0x7fff + ((u >> 16) & 1);
  return (unsigned short)(u >> 16);
}

// Vectorized prep: blocks 0..1023 convert x (8 rows/block), 1024..1535 convert y
// (16 rows/block). Per-row sq norms of ROUNDED values via in-wave shuffles.
// Blocks 0..15 also zero the 16384-float rX/rY accumulator region.
__global__ void prep_kernel(const float* __restrict__ xs, const float* __restrict__ ys,
                            unsigned short* __restrict__ xb, unsigned short* __restrict__ yb,
                            float* __restrict__ sqx, float* __restrict__ sqy,
                            float* __restrict__ rXY) {
  int b = blockIdx.x, t = threadIdx.x;
  int w = t >> 6, lane = t & 63;
  if (b < 16) {
    *(f32x4*)&rXY[b * 1024 + t * 4] = (f32x4){0.f, 0.f, 0.f, 0.f};
  }
  if (b < 1024) {           // x: wave = 2 rows of 128
    int rb = b * 8 + w * 2;
    long base = (long)rb * DX + lane * 4;
    f32x4 v = *(const f32x4*)&xs[base];
    u16x4 o; float s = 0.f;
    #pragma unroll
    for (int k = 0; k < 4; ++k) {
      unsigned short h = f32_to_bf16_rne(v[k]);
      o[k] = h;
      float bv = __uint_as_float(((unsigned int)h) << 16);
      s += bv * bv;
    }
    *(u16x4*)&xb[base] = o;
    #pragma unroll
    for (int m = 1; m <= 16; m <<= 1) s += __shfl_xor(s, m);
    if ((lane & 31) == 0) sqx[rb + (lane >> 5)] = s;
  } else {                  // y: wave = 4 rows of 64
    int rb = (b - 1024) * 16 + w * 4;
    long base = (long)rb * DY + lane * 4;
    f32x4 v = *(const f32x4*)&ys[base];
    u16x4 o; float s = 0.f;
    #pragma unroll
    for (int k = 0; k < 4; ++k) {
      unsigned short h = f32_to_bf16_rne(v[k]);
      o[k] = h;
      float bv = __uint_as_float(((unsigned int)h) << 16);
      s += bv * bv;
    }
    *(u16x4*)&yb[base] = o;
    #pragma unroll
    for (int m = 1; m <= 8; m <<= 1) s += __shfl_xor(s, m);
    if ((lane & 15) == 0) sqy[rb + (lane >> 4)] = s;
  }
}

// One K=64 chunk: each wave (w=0..7) owns a 16-row strip; 16 MFMAs.
__device__ __forceinline__ void mfma_strip(const unsigned short* __restrict__ A,
                                           const unsigned short* __restrict__ B,
                                           f32x4 acc[8], int w, int quad, int c0) {
  #pragma unroll
  for (int ks = 0; ks < 2; ++ks) {
    int koff = ks * 32 + quad * 8;
    bf16x8 a = *(const bf16x8*)&A[(w * 16 + c0) * PITCH + koff];
    #pragma unroll
    for (int tn = 0; tn < 8; ++tn) {
      bf16x8 b = *(const bf16x8*)&B[(tn * 16 + c0) * PITCH + koff];
      acc[tn] = __builtin_amdgcn_mfma_f32_16x16x32_bf16(a, b, acc[tn], 0, 0, 0);
    }
  }
}

// One block (512 thr = 8 waves) per upper-triangle 128x128 tile (bi <= bj).
// 32+32 accumulators/lane -> ~115 regs -> 4 waves/SIMD (2 blocks/CU resident).
__global__ __launch_bounds__(512, 4)
void tiles_kernel(const unsigned short* __restrict__ xb,
                  const unsigned short* __restrict__ yb,
                  const float* __restrict__ sqx,
                  const float* __restrict__ sqy,
                  float* __restrict__ rX, float* __restrict__ rY,
                  float* __restrict__ S1arr) {
  // Staging arena (2 x 128 x PITCH bf16 = 36864 B), re-aliased as the
  // row/col reduction scratch after the last MFMA.
  __shared__ char arena[2 * 128 * PITCH * 2];
  __shared__ float sq_is[2][128], sq_js[2][128];
  __shared__ float red[8];

  unsigned short* A = (unsigned short*)arena;
  unsigned short* B = A + 128 * PITCH;
  float* rowS = (float*)arena;          // [2][128][17] floats = 17408 B
  float* colS = (float*)arena + 4352;   // [2][128][9]  floats =  9216 B

  const int q = blockIdx.x;
  double disc = 16641.0 - 8.0 * q;      // (2*NB+1)^2 - 8q
  int bi = (int)((129.0 - __builtin_sqrt(disc)) * 0.5);
  while ((bi + 1) * NB - ((bi + 1) * bi) / 2 <= q) ++bi;
  while (bi * NB - (bi * (bi - 1)) / 2 > q) --bi;
  const int bj = bi + (q - (bi * NB - (bi * (bi - 1)) / 2));
  const int I = bi * 128, J = bj * 128;

  const int t = threadIdx.x;
  const int lane = t & 63, w = t >> 6;        // w: 0..7 (row strip)
  const int quad = lane >> 4, c0 = lane & 15;
  const int cc = t & 7, r0 = t >> 3;          // staging: r0 0..63, 2 passes

  f32x4 accx[8], accy[8];
  const f32x4 zero = {0.f, 0.f, 0.f, 0.f};
  #pragma unroll
  for (int n = 0; n < 8; ++n) { accx[n] = zero; accy[n] = zero; }

  // ---- stage Y (both sides) + sq ----
  #pragma unroll
  for (int p = 0; p < 2; ++p) {
    int r = r0 + p * 64;
    *(u16x8*)&A[r * PITCH + cc * 8] = *(const u16x8*)&yb[(long)(I + r) * DY + cc * 8];
    *(u16x8*)&B[r * PITCH + cc * 8] = *(const u16x8*)&yb[(long)(J + r) * DY + cc * 8];
  }
  { int u = t & 127;
    if      (t < 128) sq_is[0][u] = sqx[I + u];
    else if (t < 256) sq_is[1][u] = sqy[I + u];
    else if (t < 384) sq_js[0][u] = sqx[J + u];
    else              sq_js[1][u] = sqy[J + u];
  }
  __syncthreads();

  // ---- prefetch X chunk0 to regs; MFMA Y under the load latency ----
  u16x8 pa[2], pb[2];
  #pragma unroll
  for (int p = 0; p < 2; ++p) {
    int r = r0 + p * 64;
    pa[p] = *(const u16x8*)&xb[(long)(I + r) * DX + cc * 8];
    pb[p] = *(const u16x8*)&xb[(long)(J + r) * DX + cc * 8];
  }
  mfma_strip(A, B, accy, w, quad, c0);
  __syncthreads();

  // ---- store X0; prefetch X chunk1 ----
  #pragma unroll
  for (int p = 0; p < 2; ++p) {
    int r = r0 + p * 64;
    *(u16x8*)&A[r * PITCH + cc * 8] = pa[p];
    *(u16x8*)&B[r * PITCH + cc * 8] = pb[p];
  }
  u16x8 qa[2], qb[2];
  #pragma unroll
  for (int p = 0; p < 2; ++p) {
    int r = r0 + p * 64;
    qa[p] = *(const u16x8*)&xb[(long)(I + r) * DX + 64 + cc * 8];
    qb[p] = *(const u16x8*)&xb[(long)(J + r) * DX + 64 + cc * 8];
  }
  __syncthreads();
  mfma_strip(A, B, accx, w, quad, c0);
  __syncthreads();
  #pragma unroll
  for (int p = 0; p < 2; ++p) {
    int r = r0 + p * 64;
    *(u16x8*)&A[r * PITCH + cc * 8] = qa[p];
    *(u16x8*)&B[r * PITCH + cc * 8] = qb[p];
  }
  __syncthreads();
  mfma_strip(A, B, accx, w, quad, c0);
  __syncthreads();   // arena LDS reads done -> safe to re-alias as scratch

  // ---- epilogue: K = exp(-d^2/2); S1, row/col partial sums ----
  // C/D layout (16x16x32): col = lane&15, row = quad*4 + reg  [m89/m91]
  float s1 = 0.f;
  float colx[8], coly[8], rowx[4], rowy[4];
  #pragma unroll
  for (int n = 0; n < 8; ++n) { colx[n] = 0.f; coly[n] = 0.f; }

  #pragma unroll
  for (int r = 0; r < 4; ++r) {
    int il = w * 16 + quad * 4 + r;
    float sxi = sq_is[0][il], syi = sq_is[1][il];
    float rxp = 0.f, ryp = 0.f;
    #pragma unroll
    for (int tn = 0; tn < 8; ++tn) {
      int jl = tn * 16 + c0;
      float dx = sxi + sq_js[0][jl] - 2.f * accx[tn][r];
      float dy = syi + sq_js[1][jl] - 2.f * accy[tn][r];
      float kx = __expf(-0.5f * dx);
      float ky = __expf(-0.5f * dy);
      rxp += kx; ryp += ky; s1 += kx * ky;
      colx[tn] += kx; coly[tn] += ky;
    }
    rowx[r] = rxp; rowy[r] = ryp;
  }

  // row partials -> LDS scratch [arr][il][c0], pitch 17
  #pragma unroll
  for (int r = 0; r < 4; ++r) {
    int il = w * 16 + quad * 4 + r;
    rowS[il * 17 + c0]        = rowx[r];
    rowS[2176 + il * 17 + c0] = rowy[r];
  }

  if (bi != bj) {
    // col partials: pre-reduce over quad (xor16/32), then [arr][jl][w], pitch 9
    #pragma unroll
    for (int tn = 0; tn < 8; ++tn) {
      float cx = colx[tn] + __shfl_xor(colx[tn], 16);
      cx += __shfl_xor(cx, 32);
      float cy = coly[tn] + __shfl_xor(coly[tn], 16);
      cy += __shfl_xor(cy, 32);
      if (quad == 0) {
        int jl = tn * 16 + c0;
        colS[jl * 9 + w]        = cx;
        colS[1152 + jl * 9 + w] = cy;
      }
    }
    s1 *= 2.f;   // strictly-upper tile counts twice in tr(GX GY)
  }

  #pragma unroll
  for (int m = 1; m <= 32; m <<= 1) s1 += __shfl_xor(s1, m);
  if (lane == 0) red[w] = s1;
  __syncthreads();

  // ---- final reduction + one atomic per thread ----
  if (t < 256) {
    int arr = t >> 7, il = t & 127;
    const float* p = rowS + arr * 2176 + il * 17;
    float s = 0.f;
    #pragma unroll
    for (int k = 0; k < 16; ++k) s += p[k];
    atomicAdd((arr ? rY : rX) + I + il, s);
  } else if (bi != bj) {
    int u = t - 256;
    int arr = u >> 7, jl = u & 127;
    const float* p = colS + arr * 1152 + jl * 9;
    float s = 0.f;
    #pragma unroll
    for (int k = 0; k < 8; ++k) s += p[k];
    atomicAdd((arr ? rY : rX) + J + jl, s);
  }
  if (t == 0) {
    float s = 0.f;
    #pragma unroll
    for (int i = 0; i < 8; ++i) s += red[i];
    S1arr[q] = s;
  }
}

__global__ void finalize_kernel(const float* __restrict__ rX, const float* __restrict__ rY,
                                const float* __restrict__ S1arr, float* __restrict__ out) {
  int t = threadIdx.x;
  float dot = 0.f, tx = 0.f, ty = 0.f, s1 = 0.f;
  #pragma unroll
  for (int i = t * 4; i < N_PTS; i += 2048) {
    f32x4 a = *(const f32x4*)&rX[i];
    f32x4 b = *(const f32x4*)&rY[i];
    #pragma unroll
    for (int k = 0; k < 4; ++k) { dot += a[k] * b[k]; tx += a[k]; ty += b[k]; }
  }
  for (int i = t; i < NTILES; i += 512) s1 += S1arr[i];
  #pragma unroll
  for (int m = 1; m <= 32; m <<= 1) {
    dot += __shfl_xor(dot, m); tx += __shfl_xor(tx, m);
    ty  += __shfl_xor(ty, m);  s1 += __shfl_xor(s1, m);
  }
  __shared__ float sd[8], sx[8], sy[8], ss[8];
  int w = t >> 6, lane = t & 63;
  if (lane == 0) { sd[w] = dot; sx[w] = tx; sy[w] = ty; ss[w] = s1; }
  __syncthreads();
  if (t == 0) {
    double D = 0, X = 0, Y = 0, S = 0;
    for (int i = 0; i < 8; ++i) { D += sd[i]; X += sx[i]; Y += sy[i]; S += ss[i]; }
    double n = (double)N_PTS;
    out[0] = (float)(S - (2.0 / n) * D + (X * Y) / (n * n));
  }
}

extern "C" void kernel_launch(void* const* d_in, const int* in_sizes, int n_in,
                              void* d_out, int out_size, void* d_ws, size_t ws_size,
                              hipStream_t stream) {
  const float* x = (const float*)d_in[0];
  const float* y = (const float*)d_in[1];
  char* ws = (char*)d_ws;
  unsigned short* xb = (unsigned short*)(ws);                 // 2 MB
  unsigned short* yb = (unsigned short*)(ws + 2097152);       // 1 MB
  float* sqx = (float*)(ws + 3145728);                        // 32 KB
  float* sqy = (float*)(ws + 3178496);                        // 32 KB
  float* rXY = (float*)(ws + 3211264);                        // rX+rY, 64 KB (zeroed by prep)
  float* rX  = rXY;
  float* rY  = rXY + N_PTS;
  float* S1arr = (float*)(ws + 3276800);                      // 2080 floats (fully written)

  prep_kernel<<<1536, 256, 0, stream>>>(x, y, xb, yb, sqx, sqy, rXY);
  tiles_kernel<<<NTILES, 512, 0, stream>>>(xb, yb, sqx, sqy, rX, rY, S1arr);
  finalize_kernel<<<1, 512, 0, stream>>>(rX, rY, S1arr, (float*)d_out);
}